// Round 2
// baseline (33269.830 us; speedup 1.0000x reference)
//
#include <hip/hip_runtime.h>
#include <math.h>

#define HID   512
#define SEQL  256
#define BATCH 2048
#define NCLS  10
#define NB    8       // batch columns per workgroup
#define KCH   17      // 16 h-chunks of K=32, + 1 chunk carrying (x, bias, zero-pad)
#define HSTR  552     // padded f16 column stride (544 slots used; 552*2B = 20-bank rotation)
#define NTILE 128     // 4 gates x 32 row-tiles of 16 rows

typedef _Float16 f16x8 __attribute__((ext_vector_type(8)));
typedef float    f32x4 __attribute__((ext_vector_type(4)));

__device__ __forceinline__ float fsig(float v)  { return 1.f / (1.f + __expf(-v)); }
__device__ __forceinline__ float ftanh(float v) { return 1.f - 2.f / (1.f + __expf(2.f * v)); }

// One-time: pack weights into MFMA A-fragment stream.
// Block blk = tile*KCH + kk is 1 KiB: lane l holds 8 f16 = A[row=16*p+(l&15)][K=kk*32+(l>>4)*8+v]
// in gate-major row space (row R = g*512 + j). Chunk kk==16 carries K=512 -> wx, K=513 -> bias.
__global__ void pack_frags(const float* __restrict__ wg, const float* __restrict__ wi,
                           const float* __restrict__ wf, const float* __restrict__ wo,
                           const float* __restrict__ gx, const float* __restrict__ ix,
                           const float* __restrict__ fx, const float* __restrict__ ox,
                           const float* __restrict__ bgp, const float* __restrict__ bip,
                           const float* __restrict__ bfp, const float* __restrict__ bop,
                           f16x8* __restrict__ wq)
{
    const int idx = blockIdx.x * 256 + threadIdx.x;
    if (idx >= NTILE * KCH * 64) return;
    const int lane = idx & 63, blk = idx >> 6;
    const int kk = blk % KCH, tile = blk / KCH;
    const int g = tile >> 5, p = tile & 31;
    const int j  = 16 * p + (lane & 15);
    const int k0 = kk * 32 + (lane >> 4) * 8;
    const float* w  = (g == 0) ? wg : (g == 1) ? wi : (g == 2) ? wf : wo;
    const float* wx = (g == 0) ? gx : (g == 1) ? ix : (g == 2) ? fx : ox;
    const float* bb = (g == 0) ? bgp : (g == 1) ? bip : (g == 2) ? bfp : bop;
    f16x8 vv;
    #pragma unroll
    for (int v = 0; v < 8; v++) {
        const int K = k0 + v;
        float f;
        if (kk < 16) {
            f = w[j * HID + K];
        } else {
            const int Kp = K - HID;
            f = (Kp == 0) ? wx[j] : (Kp == 1) ? bb[j] : 0.f;
        }
        vv[v] = (_Float16)f;
    }
    wq[blk * 64 + lane] = vv;
}

// Persistent MFMA LSTM. Grid 256 WGs x 512 threads (8 waves). Wave w owns row-tiles
// {g*32 + w + 8*pi : g=0..3, pi=0..3} so (g,i,f,o) rows with matching j are lane-local.
// h' lives in LDS f16 [col][k] (double-buffered); weights stream from L2 as pre-packed
// A-fragments, pipelined 8 fragments ahead.
__global__ __launch_bounds__(512, 2) void lstm_mfma(
    const float* __restrict__ x,                                   // [B][SEQ]
    const f16x8* __restrict__ wq,                                  // packed fragments
    const float* __restrict__ wph, const float* __restrict__ bp,   // [C][H], [C]
    const float* __restrict__ h_init, const float* __restrict__ c_init, // [H]
    float* __restrict__ out)                                       // [B][C]
{
    __shared__ __align__(16) _Float16 hbuf[2][16][HSTR];  // 34.5 KB
    __shared__ float x_s[NB][SEQL];                       // 8 KB

    const int tid  = threadIdx.x;
    const int lane = tid & 63;
    const int wv   = tid >> 6;          // wave 0..7
    const int col  = lane & 15;         // B/C fragment column (batch col; >=8 dead)
    const int kq   = lane >> 4;         // k-quadrant
    const int b0   = blockIdx.x * NB;

    for (int i = tid; i < NB * SEQL; i += 512)
        x_s[i / SEQL][i % SEQL] = x[(b0 + i / SEQL) * SEQL + (i % SEQL)];
    __syncthreads();

    // Init h' buffers: buf0 = [h_init | x_0 | 1 | 0...], buf1 = [* | * | 1 | 0...]
    // (cols >= NB stay all-zero forever -> their MFMA outputs are exactly 0).
    for (int i = tid; i < 2 * 16 * HSTR; i += 512) {
        const int b = i / (16 * HSTR), rem = i % (16 * HSTR);
        const int c = rem / HSTR, k = rem % HSTR;
        float v = 0.f;
        if (c < NB) {
            if (k < HID)            v = (b == 0) ? h_init[k] : 0.f;
            else if (k == HID)      v = (b == 0) ? x_s[c][0] : 0.f;
            else if (k == HID + 1)  v = 1.f;
        }
        ((_Float16*)hbuf)[i] = (_Float16)v;
    }

    // Cell state for this lane's 16 rows: j = 16*(wv+8*pi) + 4*kq + r
    float creg[4][4];
    #pragma unroll
    for (int pi = 0; pi < 4; pi++) {
        const int j0 = 16 * (wv + 8 * pi) + 4 * kq;
        #pragma unroll
        for (int r = 0; r < 4; r++) creg[pi][r] = c_init[j0 + r];
    }

    // Fragment-stream base offsets (f16x8 units) per (gate, pi).
    int tofs[4][4];
    #pragma unroll
    for (int g = 0; g < 4; g++)
        #pragma unroll
        for (int pi = 0; pi < 4; pi++)
            tofs[g][pi] = ((g * 32 + wv + 8 * pi) * KCH) * 64 + lane;

    __syncthreads();

    #pragma unroll 1
    for (int t = 0; t < SEQL; t++) {
        const int rb = t & 1;
        const _Float16* hb = &hbuf[rb][col][kq * 8];

        f32x4 acc[4][4];
        #pragma unroll
        for (int g = 0; g < 4; g++)
            #pragma unroll
            for (int pi = 0; pi < 4; pi++)
                acc[g][pi] = (f32x4){0.f, 0.f, 0.f, 0.f};

        // Half-chunk pipeline: hc covers (kk = hc/2, gates gh..gh+1), 8 frags per half.
        // 34 halves (even) -> buffer parity consistent every step.
        f16x8 A[2][2][4];
        #pragma unroll
        for (int gg = 0; gg < 2; gg++)
            #pragma unroll
            for (int pi = 0; pi < 4; pi++)
                A[0][gg][pi] = wq[tofs[gg][pi]];          // kk=0, gates 0..1

        #pragma unroll
        for (int hc = 0; hc < 34; hc++) {
            const int kk = hc >> 1;
            const int gh = (hc & 1) * 2;
            const int pb = hc & 1;
            if (hc < 33) {                                 // prefetch next half
                const int nk  = (hc + 1) >> 1;
                const int ngh = ((hc + 1) & 1) * 2;
                #pragma unroll
                for (int gg = 0; gg < 2; gg++)
                    #pragma unroll
                    for (int pi = 0; pi < 4; pi++)
                        A[pb ^ 1][gg][pi] = wq[tofs[ngh + gg][pi] + nk * 64];
            }
            const f16x8 B = *(const f16x8*)(hb + kk * 32);
            #pragma unroll
            for (int gg = 0; gg < 2; gg++)
                #pragma unroll
                for (int pi = 0; pi < 4; pi++)
                    acc[gh + gg][pi] = __builtin_amdgcn_mfma_f32_16x16x32_f16(
                        A[pb][gg][pi], B, acc[gh + gg][pi], 0, 0, 0);
        }

        // Nonlinearity (lane-local: all 4 gates at identical (lane,reg) positions).
        const int wb = rb ^ 1;
        #pragma unroll
        for (int pi = 0; pi < 4; pi++) {
            const int j0 = 16 * (wv + 8 * pi) + 4 * kq;
            #pragma unroll
            for (int r = 0; r < 4; r++) {
                const float pg  = acc[0][pi][r];
                const float pii = acc[1][pi][r];
                const float pf  = acc[2][pi][r];
                const float po  = acc[3][pi][r];
                const float cc  = ftanh(pg) * fsig(pii) + creg[pi][r] * fsig(pf);
                creg[pi][r] = cc;
                if (col < NB)
                    hbuf[wb][col][j0 + r] = (_Float16)(ftanh(cc) * fsig(po));
            }
        }
        if (tid < NB) {
            const int tn = (t + 1 < SEQL) ? t + 1 : t;
            hbuf[wb][tid][HID] = (_Float16)x_s[tid][tn];
        }
        __syncthreads();
    }

    // Epilogue: out[b][cls] = bp[cls] + sum_k wph[cls][k] * h[k][b]; final h in hbuf[0].
    if (tid < NB * NCLS) {
        const int c = tid / NCLS, cls = tid - c * NCLS;
        float s = bp[cls];
        for (int k = 0; k < HID; k++)
            s = fmaf(wph[cls * HID + k], (float)hbuf[0][c][k], s);
        out[(b0 + c) * NCLS + cls] = s;
    }
}

extern "C" void kernel_launch(void* const* d_in, const int* in_sizes, int n_in,
                              void* d_out, int out_size, void* d_ws, size_t ws_size,
                              hipStream_t stream)
{
    const float* x   = (const float*)d_in[0];
    const float* wgx = (const float*)d_in[1];
    const float* wix = (const float*)d_in[2];
    const float* wfx = (const float*)d_in[3];
    const float* wox = (const float*)d_in[4];
    const float* wgh = (const float*)d_in[5];
    const float* wih = (const float*)d_in[6];
    const float* wfh = (const float*)d_in[7];
    const float* woh = (const float*)d_in[8];
    const float* bg  = (const float*)d_in[9];
    const float* bi  = (const float*)d_in[10];
    const float* bf  = (const float*)d_in[11];
    const float* bo  = (const float*)d_in[12];
    const float* wph = (const float*)d_in[13];
    const float* bp  = (const float*)d_in[14];
    const float* h0  = (const float*)d_in[15];
    const float* c0  = (const float*)d_in[16];
    float* out = (float*)d_out;
    f16x8* wq  = (f16x8*)d_ws;   // 128*17*1024 B = 2.125 MiB packed fragments

    pack_frags<<<dim3((NTILE * KCH * 64 + 255) / 256), dim3(256), 0, stream>>>(
        wgh, wih, wfh, woh, wgx, wix, wfx, wox, bg, bi, bf, bo, wq);
    lstm_mfma<<<dim3(BATCH / NB), dim3(512), 0, stream>>>(
        x, wq, wph, bp, h0, c0, out);
}

// Round 4
// 4639.682 us; speedup vs baseline: 7.1707x; 7.1707x over previous
//
#include <hip/hip_runtime.h>
#include <math.h>

#define HID   512
#define SEQL  256
#define BATCH 2048
#define NCLS  10
#define NB    16      // batch columns per workgroup = full MFMA tile width
#define KCH   17      // 16 h-chunks of K=32, + 1 chunk carrying (x, bias, zero-pad)
#define HSTR  552     // padded f16 column stride (544 used; 552*2B -> bank stride 20)
#define NTILE 128     // 4 gates x 32 row-tiles of 16 rows

typedef _Float16 f16x8 __attribute__((ext_vector_type(8)));
typedef _Float16 f16x4 __attribute__((ext_vector_type(4)));
typedef float    f32x4 __attribute__((ext_vector_type(4)));

__device__ __forceinline__ float fsig(float v)  { return 1.f / (1.f + __expf(-v)); }
__device__ __forceinline__ float ftanh(float v) { return 1.f - 2.f / (1.f + __expf(2.f * v)); }

// One-time: pack weights into MFMA A-fragment stream.
// Block blk = tile*KCH + kk is 1 KiB: lane l holds 8 f16 = A[row=16*p+(l&15)][K=kk*32+(l>>4)*8+v]
// in gate-major row space (row R = g*512 + j). Chunk kk==16 carries K=512 -> wx, K=513 -> bias.
__global__ void pack_frags(const float* __restrict__ wg, const float* __restrict__ wi,
                           const float* __restrict__ wf, const float* __restrict__ wo,
                           const float* __restrict__ gx, const float* __restrict__ ix,
                           const float* __restrict__ fx, const float* __restrict__ ox,
                           const float* __restrict__ bgp, const float* __restrict__ bip,
                           const float* __restrict__ bfp, const float* __restrict__ bop,
                           f16x8* __restrict__ wq)
{
    const int idx = blockIdx.x * 256 + threadIdx.x;
    if (idx >= NTILE * KCH * 64) return;
    const int lane = idx & 63, blk = idx >> 6;
    const int kk = blk % KCH, tile = blk / KCH;
    const int g = tile >> 5, p = tile & 31;
    const int j  = 16 * p + (lane & 15);
    const int k0 = kk * 32 + (lane >> 4) * 8;
    const float* w  = (g == 0) ? wg : (g == 1) ? wi : (g == 2) ? wf : wo;
    const float* wx = (g == 0) ? gx : (g == 1) ? ix : (g == 2) ? fx : ox;
    const float* bb = (g == 0) ? bgp : (g == 1) ? bip : (g == 2) ? bfp : bop;
    f16x8 vv;
    #pragma unroll
    for (int v = 0; v < 8; v++) {
        const int K = k0 + v;
        float f;
        if (kk < 16) {
            f = w[j * HID + K];
        } else {
            const int Kp = K - HID;
            f = (Kp == 0) ? wx[j] : (Kp == 1) ? bb[j] : 0.f;
        }
        vv[v] = (_Float16)f;
    }
    wq[blk * 64 + lane] = vv;
}

// Persistent MFMA LSTM. 128 WGs x 512 threads (8 waves); WG owns 16 batch cols
// (full 16x16 MFMA tile width). Wave wv owns row-tiles {g*32 + wv + 8*pi}.
// h' in LDS f16 [col][k] double-buffered, 1 barrier/step; weights stream from L2
// as pre-packed A-fragments, half-chunk (8-frag) static double buffer A0/A1.
// NOTE __launch_bounds__(512,1): R2's (512,2) capped VGPRs at 128 -> 60-reg spill
// -> 485 MB scratch churn -> L2 thrash (62 GB fetch). This kernel needs ~200 regs.
__global__ __launch_bounds__(512, 1) void lstm_mfma(
    const float* __restrict__ x,                                   // [B][SEQ]
    const f16x8* __restrict__ wq,                                  // packed fragments
    const float* __restrict__ wph, const float* __restrict__ bp,   // [C][H], [C]
    const float* __restrict__ h_init, const float* __restrict__ c_init, // [H]
    float* __restrict__ out)                                       // [B][C]
{
    __shared__ __align__(16) _Float16 hbuf[2][NB][HSTR];  // 34.5 KB
    __shared__ float x_s[NB][SEQL];                       // 16 KB

    const int tid  = threadIdx.x;
    const int lane = tid & 63;
    const int wv   = tid >> 6;          // wave 0..7
    const int col  = lane & 15;         // B/C fragment column = batch col (all 16 live)
    const int kq   = lane >> 4;         // k-quadrant
    const int b0   = blockIdx.x * NB;

    for (int i = tid; i < NB * SEQL; i += 512)
        x_s[i / SEQL][i % SEQL] = x[(b0 + i / SEQL) * SEQL + (i % SEQL)];
    __syncthreads();

    // Init h' buffers: buf0 = [h_init | x_0 | 1 | pad], buf1 = [0 | 0 | 1 | pad].
    for (int i = tid; i < 2 * NB * HSTR; i += 512) {
        const int b = i / (NB * HSTR), rem = i % (NB * HSTR);
        const int c = rem / HSTR, k = rem % HSTR;
        float v = 0.f;
        if (k < HID)            v = (b == 0) ? h_init[k] : 0.f;
        else if (k == HID)      v = (b == 0) ? x_s[c][0] : 0.f;
        else if (k == HID + 1)  v = 1.f;
        ((_Float16*)hbuf)[i] = (_Float16)v;
    }

    // Cell state: lane covers rows j0..j0+3 (per pi) of its column.
    float creg[4][4];
    #pragma unroll
    for (int pi = 0; pi < 4; pi++) {
        const int j0 = 16 * (wv + 8 * pi) + 4 * kq;
        #pragma unroll
        for (int r = 0; r < 4; r++) creg[pi][r] = c_init[j0 + r];
    }

    // Fragment-stream base offsets (f16x8 units) per (gate, pi).
    int tofs[4][4];
    #pragma unroll
    for (int g = 0; g < 4; g++)
        #pragma unroll
        for (int pi = 0; pi < 4; pi++)
            tofs[g][pi] = ((g * 32 + wv + 8 * pi) * KCH) * 64 + lane;

    __syncthreads();

    #pragma unroll 1
    for (int t = 0; t < SEQL; t++) {
        const int rb = t & 1;
        const _Float16* hb = &hbuf[rb][col][kq * 8];

        f32x4 acc[4][4];   // [gate][pi] — every index below is compile-time
        #pragma unroll
        for (int g = 0; g < 4; g++)
            #pragma unroll
            for (int pi = 0; pi < 4; pi++)
                acc[g][pi] = (f32x4){0.f, 0.f, 0.f, 0.f};

        // Prologue: A0 <- (kk=0, gates 0..1); B <- chunk 0.
        f16x8 A0[8], A1[8];
        #pragma unroll
        for (int gg = 0; gg < 2; gg++)
            #pragma unroll
            for (int pi = 0; pi < 4; pi++)
                A0[gg * 4 + pi] = wq[tofs[gg][pi]];
        f16x8 Bc = *(const f16x8*)(hb);

        #pragma unroll 1
        for (int m = 0; m < KCH; m++) {
            const int mn = (m < KCH - 1) ? m + 1 : KCH - 1;  // clamped next chunk
            // issue A1 <- (m, gates 2..3)
            #pragma unroll
            for (int gg = 0; gg < 2; gg++)
                #pragma unroll
                for (int pi = 0; pi < 4; pi++)
                    A1[gg * 4 + pi] = wq[tofs[2 + gg][pi] + m * 64];
            // compute gates 0..1 with A0
            #pragma unroll
            for (int gg = 0; gg < 2; gg++)
                #pragma unroll
                for (int pi = 0; pi < 4; pi++)
                    acc[gg][pi] = __builtin_amdgcn_mfma_f32_16x16x32_f16(
                        A0[gg * 4 + pi], Bc, acc[gg][pi], 0, 0, 0);
            // issue A0 <- (m+1, gates 0..1)
            #pragma unroll
            for (int gg = 0; gg < 2; gg++)
                #pragma unroll
                for (int pi = 0; pi < 4; pi++)
                    A0[gg * 4 + pi] = wq[tofs[gg][pi] + mn * 64];
            // B for next chunk (issued before the g23 MFMAs to hide LDS latency)
            const f16x8 Bn = *(const f16x8*)(hb + mn * 32);
            // compute gates 2..3 with A1
            #pragma unroll
            for (int gg = 0; gg < 2; gg++)
                #pragma unroll
                for (int pi = 0; pi < 4; pi++)
                    acc[2 + gg][pi] = __builtin_amdgcn_mfma_f32_16x16x32_f16(
                        A1[gg * 4 + pi], Bc, acc[2 + gg][pi], 0, 0, 0);
            Bc = Bn;
        }

        // Nonlinearity: all 4 gates live at identical (lane, reg) positions.
        const int wb = rb ^ 1;
        #pragma unroll
        for (int pi = 0; pi < 4; pi++) {
            const int j0 = 16 * (wv + 8 * pi) + 4 * kq;
            f16x4 hv4;
            #pragma unroll
            for (int r = 0; r < 4; r++) {
                const float pg  = acc[0][pi][r];
                const float pii = acc[1][pi][r];
                const float pf  = acc[2][pi][r];
                const float po  = acc[3][pi][r];
                const float cc  = ftanh(pg) * fsig(pii) + creg[pi][r] * fsig(pf);
                creg[pi][r] = cc;
                hv4[r] = (_Float16)(ftanh(cc) * fsig(po));
            }
            *(f16x4*)&hbuf[wb][col][j0] = hv4;   // 8B store, 8B-aligned
        }
        if (tid < NB) {
            const int tn = (t + 1 < SEQL) ? t + 1 : t;
            hbuf[wb][tid][HID] = (_Float16)x_s[tid][tn];
        }
        __syncthreads();
    }

    // Epilogue: out[b][cls] = bp[cls] + sum_k wph[cls][k] * h[k][b]; final h in hbuf[0].
    if (tid < NB * NCLS) {
        const int c = tid / NCLS, cls = tid - c * NCLS;
        float s = bp[cls];
        for (int k = 0; k < HID; k++)
            s = fmaf(wph[cls * HID + k], (float)hbuf[0][c][k], s);
        out[(b0 + c) * NCLS + cls] = s;
    }
}

extern "C" void kernel_launch(void* const* d_in, const int* in_sizes, int n_in,
                              void* d_out, int out_size, void* d_ws, size_t ws_size,
                              hipStream_t stream)
{
    const float* x   = (const float*)d_in[0];
    const float* wgx = (const float*)d_in[1];
    const float* wix = (const float*)d_in[2];
    const float* wfx = (const float*)d_in[3];
    const float* wox = (const float*)d_in[4];
    const float* wgh = (const float*)d_in[5];
    const float* wih = (const float*)d_in[6];
    const float* wfh = (const float*)d_in[7];
    const float* woh = (const float*)d_in[8];
    const float* bg  = (const float*)d_in[9];
    const float* bi  = (const float*)d_in[10];
    const float* bf  = (const float*)d_in[11];
    const float* bo  = (const float*)d_in[12];
    const float* wph = (const float*)d_in[13];
    const float* bp  = (const float*)d_in[14];
    const float* h0  = (const float*)d_in[15];
    const float* c0  = (const float*)d_in[16];
    float* out = (float*)d_out;
    f16x8* wq  = (f16x8*)d_ws;   // 128*17*1024 B = 2.125 MiB packed fragments

    pack_frags<<<dim3((NTILE * KCH * 64 + 255) / 256), dim3(256), 0, stream>>>(
        wgh, wih, wfh, woh, wgx, wix, wfx, wox, bg, bi, bf, bo, wq);
    lstm_mfma<<<dim3(BATCH / NB), dim3(512), 0, stream>>>(
        x, wq, wph, bp, h0, c0, out);
}